// Round 6
// baseline (257.940 us; speedup 1.0000x reference)
//
#include <hip/hip_runtime.h>
#include <stdint.h>

typedef __bf16 bf16;
typedef float  f32x4  __attribute__((ext_vector_type(4)));
typedef float  f32x16 __attribute__((ext_vector_type(16)));
typedef float  float4v __attribute__((ext_vector_type(4)));
typedef bf16   bf16x8 __attribute__((ext_vector_type(8)));
typedef bf16   bf16x4 __attribute__((ext_vector_type(4)));

#define B_ 4
#define S_ 2048
#define D_ 1024
#define H_ 16
#define E_ 64
#define M_ 8192   // B_*S_
// Q prescale: 1/sqrt(E) * log2(e)  -> scores come out in log2 domain
#define QSCALE 0.18033688f

// NOTE (session journal): inline `s_waitcnt` asm and prefetch-after-barrier
// staging each killed the MI355X container twice in the prior session.
// Stage -> __syncthreads -> compute is proven. Do not reintroduce either.
// R1: attn 512-thr / 8-wave blocks, 128-row q-tile pair {A,15-A}: 61.5->~58us.
// R3 FAILED: KVBLK=128 + V-direct-from-global -> 160us. V MUST stay LDS-staged
//   (PV re-reads the V tile 16x). wall - sum(dispatch) ~ 75us is FIXED harness
//   overhead (same at 5 and 7 launches) -> kernel fusion not a lever.
// R4: attn v5 + T5 setprio -> 253.6us; gemm_qkv top dispatch at 60us = 858 TF.
// R5: __launch_bounds__(256,4) NEUTRAL (58.5us, occ 29%) -> residency not
//   register-limited; gemm is AT the 2-barrier structural ceiling (~880 TF).
//   All documented paths past it (counted vmcnt, dbuf prefetch) are on the
//   container-killer list. Remaining lever: compute-phase efficiency.
// R6 (this round): gemm128 -> 32x32x16 MFMA (4061 vs 3378 FLOP/cyc, m119):
//   ~17% less matrix-pipe time, half the MFMA instructions, same ds_read
//   count/swizzle. C-layout col=lane&31, row=(reg&3)+8*(reg>>2)+4*(lane>>5).
//   If neutral -> compute phase fully stall-shadowed -> attn next.

// async global->LDS, 16B per lane. LDS dest must be wave-uniform base + lane*16.
__device__ __forceinline__ void async_ld16(const bf16* g, bf16* l) {
  __builtin_amdgcn_global_load_lds(
      (const __attribute__((address_space(1))) void*)g,
      (__attribute__((address_space(3))) void*)l, 16, 0, 0);
}

// ---------------- fused pack kernel ----------------
// blocks [0,8192): x f32 -> bf16 cast (no LDS, no sync)
// blocks [8192,8960): Wq/Wk/Wv [H][D][E] -> Bt[n][d], n = qkv*1024+h*64+e
// blocks [8960,9216): Wo [K][N] -> Wot[n][k]

__global__ __launch_bounds__(256) void packs(
    const float* __restrict__ x, const float* __restrict__ Wq,
    const float* __restrict__ Wk, const float* __restrict__ Wv,
    const float* __restrict__ Wo, bf16* __restrict__ xb,
    bf16* __restrict__ Bt, bf16* __restrict__ Wot) {
  __shared__ float t[64][65];
  const int bid = blockIdx.x;
  if (bid < 8192) {                       // ---- pack_x: 8192*256 float4 ----
    int i = bid * 256 + threadIdx.x;      // n4 = 2097152 exactly = 8192*256
    float4v v = ((const float4v*)x)[i];
    bf16x4 o = { (bf16)v.x, (bf16)v.y, (bf16)v.z, (bf16)v.w };
    ((bf16x4*)xb)[i] = o;
    return;
  }
  const int tr = threadIdx.x >> 2;        // 0..63
  const int tc = (threadIdx.x & 3) * 16;  // 0,16,32,48
  if (bid < 8960) {                       // ---- pack_wqkv: 768 blocks ----
    const int fb = bid - 8192;
    const int mat = fb % 48;              // qkv*16 + h
    const int d0 = (fb / 48) * 64;
    const int qkv = mat >> 4, h = mat & 15;
    const float* W = (qkv == 0) ? Wq : ((qkv == 1) ? Wk : Wv);
    const float* src = W + h * (D_ * E_);           // [d][e]
    for (int i = 0; i < 16; ++i) t[tr][tc + i] = src[(d0 + tr) * E_ + tc + i];
    __syncthreads();
    const int n = qkv * 1024 + h * 64 + tr;         // output row (e dim)
    bf16* dst = Bt + n * D_ + d0 + tc;
    for (int i = 0; i < 16; ++i) dst[i] = (bf16)t[tc + i][tr];
  } else {                                // ---- pack_wo: 256 blocks ----
    const int fb = bid - 8960;
    const int k0 = (fb & 15) * 64, n0 = (fb >> 4) * 64;
    for (int i = 0; i < 16; ++i) t[tr][tc + i] = Wo[(k0 + tr) * D_ + n0 + tc + i];
    __syncthreads();
    bf16* dst = Wot + (n0 + tr) * D_ + k0 + tc;
    for (int i = 0; i < 16; ++i) dst[i] = (bf16)t[tc + i][tr];
  }
}

// ------- 128x128 MFMA GEMM (m97 staging structure, 32x32x16 MFMA core) -------
// Per wave: 64x64 output = 2x2 tiles of 32x32. A-frag: row=lane&31,
// k=(lane>>5)*8+j -> LDS chunk s*2+(lane>>5), XOR-swizzled by (row&7).
// C/D layout: col=lane&31, row=(reg&3)+8*(reg>>2)+4*(lane>>5)  [m74/m101].

template <int EPI>
__global__ __launch_bounds__(256, 4) void gemm128(
    const bf16* __restrict__ A, const bf16* __restrict__ Bt, int K,
    bf16* __restrict__ qo, bf16* __restrict__ ko, bf16* __restrict__ vt,
    const float* __restrict__ xres, float* __restrict__ outp) {
  __shared__ bf16 As[128 * 64];
  __shared__ bf16 Bs[128 * 64];
  const int tid = threadIdx.x;
  const int wave = tid >> 6, lane = tid & 63;
  const int l5 = lane & 31, hi = lane >> 5;
  const int wr = wave >> 1, wc = wave & 1;
  const int m0 = blockIdx.y * 128, n0 = blockIdx.x * 128;
  f32x16 acc[2][2] = {};

  for (int kt = 0; kt < K; kt += 64) {
    for (int it = 0; it < 4; ++it) {
      int cl = it * 256 + tid;       // chunk id 0..1023 (16B chunks)
      int r = cl >> 3, pc = cl & 7;
      int cc = pc ^ (r & 7);         // source column-chunk (XOR swizzle, self-inverse)
      async_ld16(A + (m0 + r) * K + kt + cc * 8, As + cl * 8);
      async_ld16(Bt + (n0 + r) * K + kt + cc * 8, Bs + cl * 8);
    }
    __syncthreads();
#pragma unroll
    for (int s = 0; s < 4; ++s) {    // 4 k-steps of 16 within the 64-wide tile
      bf16x8 af[2], bfr[2];
      const int cb = s * 2 + hi;
#pragma unroll
      for (int ti = 0; ti < 2; ++ti) {
        int row = wr * 64 + ti * 32 + l5;
        af[ti] = *(const bf16x8*)(As + row * 64 + (cb ^ (row & 7)) * 8);
      }
#pragma unroll
      for (int tj = 0; tj < 2; ++tj) {
        int row = wc * 64 + tj * 32 + l5;
        bfr[tj] = *(const bf16x8*)(Bs + row * 64 + (cb ^ (row & 7)) * 8);
      }
#pragma unroll
      for (int ti = 0; ti < 2; ++ti)
#pragma unroll
        for (int tj = 0; tj < 2; ++tj)
          acc[ti][tj] = __builtin_amdgcn_mfma_f32_32x32x16_bf16(af[ti], bfr[tj], acc[ti][tj], 0, 0, 0);
    }
    __syncthreads();
  }

  if (EPI == 0) {
    const int qkv = n0 >> 10;                    // uniform per block (1024%128==0)
    const int hh = ((n0 + wc * 64) >> 6) & 15;   // uniform per wave (tj*32 < 64)
#pragma unroll
    for (int ti = 0; ti < 2; ++ti)
#pragma unroll
      for (int tj = 0; tj < 2; ++tj) {
        const int e = tj * 32 + l5;              // 0..63 within head
#pragma unroll
        for (int rr = 0; rr < 4; ++rr) {         // reg groups: rows rr*8+4*hi +0..3
          const int gm0 = m0 + wr * 64 + ti * 32 + rr * 8 + hi * 4;
          const int b = gm0 >> 11, s0 = gm0 & 2047;  // 4 rows share b (gm0 % 4 == 0)
          if (qkv == 2) {
            bf16x4 pv = { (bf16)acc[ti][tj][rr * 4 + 0], (bf16)acc[ti][tj][rr * 4 + 1],
                          (bf16)acc[ti][tj][rr * 4 + 2], (bf16)acc[ti][tj][rr * 4 + 3] };
            *(bf16x4*)(vt + (((b << 4) + hh) * 64 + e) * (size_t)S_ + s0) = pv;
          } else if (qkv == 0) {
            for (int r = 0; r < 4; ++r)
              qo[(((b << 4) + hh) * S_ + (s0 + r)) * (size_t)E_ + e] =
                  (bf16)(acc[ti][tj][rr * 4 + r] * QSCALE);  // fold 1/sqrt(E)*log2e
          } else {
            for (int r = 0; r < 4; ++r)
              ko[(((b << 4) + hh) * S_ + (s0 + r)) * (size_t)E_ + e] =
                  (bf16)acc[ti][tj][rr * 4 + r];
          }
        }
      }
  } else {
#pragma unroll
    for (int ti = 0; ti < 2; ++ti)
#pragma unroll
      for (int tj = 0; tj < 2; ++tj) {
        const int gn = n0 + wc * 64 + tj * 32 + l5;
#pragma unroll
        for (int rr = 0; rr < 4; ++rr) {
          const int gm0 = m0 + wr * 64 + ti * 32 + rr * 8 + hi * 4;
          for (int r = 0; r < 4; ++r) {
            const int gm = gm0 + r;
            outp[gm * (size_t)D_ + gn] = acc[ti][tj][rr * 4 + r] + xres[gm * (size_t)D_ + gn];
          }
        }
      }
  }
}

// -------- flash attention v5 (proven) + T5 setprio ------------------------
// Q,K: [B,H,S,E] bf16 (Q pre-scaled by log2e/8 -> scores in log2 domain).
// Vt: [B,H,E,S] bf16. Block = (b,h, q-128-tile pair {At, 15-At}); 8 waves,
// wave w owns rows w*16 of BOTH tiles -> per-iteration work balanced.
// K and V both LDS-staged (R3 lesson). Stage -> sync -> compute, dbuf, proven.

__global__ __launch_bounds__(512, 4) void attn(
    const bf16* __restrict__ Q, const bf16* __restrict__ Kb,
    const bf16* __restrict__ Vt, bf16* __restrict__ Hd) {
  __shared__ __align__(16) bf16 Ks[2][64 * 64];
  __shared__ __align__(16) bf16 Vs[2][64 * 64];
  __shared__ __align__(16) bf16 Pb[8][16 * 64];   // per-wave P (t-shared)
  const int tid = threadIdx.x;
  const int w = tid >> 6, lane = tid & 63;
  const int lm = lane & 15, quad = lane >> 4;
  const int l7 = lm & 7;
  const int bi = blockIdx.x;
  const int bh = bi & 63;             // b*16+h
  const int At = bi >> 6;             // 0..7 : q-128-tile pair {At, 15-At}
  const bf16* Qp = Q + (size_t)bh * S_ * E_;
  const bf16* Kp = Kb + (size_t)bh * S_ * E_;
  const bf16* Vp = Vt + (size_t)bh * E_ * S_;

  int qb[2], sq[2];
  bf16x8 qf[2][2];
  qb[0] = At * 128 + w * 16;
  qb[1] = (15 - At) * 128 + w * 16;
#pragma unroll
  for (int t = 0; t < 2; ++t) {
    sq[t] = qb[t] + lm;
    qf[t][0] = *(const bf16x8*)(Qp + sq[t] * E_ + quad * 8);
    qf[t][1] = *(const bf16x8*)(Qp + sq[t] * E_ + 32 + quad * 8);
  }
  float ls[2] = { 0.0f, 0.0f };       // per-lane partial row sums
  f32x4 oacc[2][4] = {};

  const int jmax = 31 - 2 * At;       // diag 64-tile of the larger q-tile
  for (int j = 0; j <= jmax; ++j) {
    const int p = j & 1;
    const int sk0 = j * 64;
    // stage K tile [sk0..sk0+63][0..63] and V^T tile [0..63][sk0..sk0+63]
    {
      int cl = tid;                   // 0..511 16B chunks (one K + one V each)
      int r = cl >> 3, pc = cl & 7;
      int cc = pc ^ (r & 7);
      async_ld16(Kp + (sk0 + r) * E_ + cc * 8, &Ks[p][cl * 8]);
      async_ld16(Vp + (size_t)r * S_ + sk0 + cc * 8, &Vs[p][cl * 8]);
    }
    __syncthreads();                  // stage -> barrier (proven structure)

#pragma unroll
    for (int t = 0; t < 2; ++t) {
      const int d = (qb[t] - sk0) >> 4;   // diagonal subtile index (wave-uniform)
      if (d < 0) continue;                // whole tile above diagonal
      // ---- QK: always all 4 sk-subtiles (compile-time unroll) ----
      f32x4 st[4] = {};
      __builtin_amdgcn_s_setprio(1);
#pragma unroll
      for (int i = 0; i < 4; ++i) {
        const int row = i * 16 + lm;
        bf16x8 k0 = *(const bf16x8*)(&Ks[p][row * 64 + (quad ^ l7) * 8]);
        st[i] = __builtin_amdgcn_mfma_f32_16x16x32_bf16(k0, qf[t][0], st[i], 0, 0, 0);
        bf16x8 k1 = *(const bf16x8*)(&Ks[p][row * 64 + ((4 + quad) ^ l7) * 8]);
        st[i] = __builtin_amdgcn_mfma_f32_16x16x32_bf16(k1, qf[t][1], st[i], 0, 0, 0);
      }
      __builtin_amdgcn_s_setprio(0);
      if (d < 4) {                        // diagonal tile: mask sk>sq
#pragma unroll
        for (int i = 0; i < 4; ++i) {
          const int base = (i - d) * 16 + quad * 4;   // <=-1 below diag
#pragma unroll
          for (int r = 0; r < 4; ++r)
            st[i][r] = (base + r > lm) ? -30000.0f : st[i][r];
        }
      }
      // ---- softmax (max-free): p = exp2(s); per-lane row-sum ----
      char* pbase = (char*)&Pb[w][0];
#pragma unroll
      for (int i = 0; i < 4; ++i) {
        const float p0 = __builtin_amdgcn_exp2f(st[i][0]);
        const float p1 = __builtin_amdgcn_exp2f(st[i][1]);
        const float p2 = __builtin_amdgcn_exp2f(st[i][2]);
        const float p3 = __builtin_amdgcn_exp2f(st[i][3]);
        ls[t] += (p0 + p1) + (p2 + p3);
        bf16x4 pv = { (bf16)p0, (bf16)p1, (bf16)p2, (bf16)p3 };
        const int c = (i * 2 + (quad >> 1)) ^ l7;
        *(bf16x4*)(pbase + lm * 128 + c * 16 + (quad & 1) * 8) = pv;
      }
      // ---- PV: O^T += V^T · P^T, 2 k-steps (compile-time) ----
      __builtin_amdgcn_s_setprio(1);
#pragma unroll
      for (int ks = 0; ks < 2; ++ks) {
        bf16x8 pf = *(const bf16x8*)(pbase + lm * 128 + ((ks * 4 + quad) ^ l7) * 16);
#pragma unroll
        for (int te = 0; te < 4; ++te) {
          const int vrow = te * 16 + lm;
          bf16x8 vf = *(const bf16x8*)(&Vs[p][vrow * 64 + ((ks * 4 + quad) ^ l7) * 8]);
          oacc[t][te] = __builtin_amdgcn_mfma_f32_16x16x32_bf16(vf, pf, oacc[t][te], 0, 0, 0);
        }
      }
      __builtin_amdgcn_s_setprio(0);
    }
  }
  const int b = bh >> 4, h = bh & 15;
#pragma unroll
  for (int t = 0; t < 2; ++t) {
    float rs = ls[t];
    rs += __shfl_xor(rs, 16);
    rs += __shfl_xor(rs, 32);
    const float inv = 1.0f / rs;
#pragma unroll
    for (int te = 0; te < 4; ++te) {
      bf16x4 ov = { (bf16)(oacc[t][te][0] * inv), (bf16)(oacc[t][te][1] * inv),
                    (bf16)(oacc[t][te][2] * inv), (bf16)(oacc[t][te][3] * inv) };
      *(bf16x4*)(&Hd[((size_t)b * S_ + sq[t]) * D_ + h * 64 + te * 16 + quad * 4]) = ov;
    }
  }
}

// ---------------- rowwise LayerNorm, in-place on f32 ----------------

__global__ __launch_bounds__(256) void lnorm(float* __restrict__ y,
                                             const float* __restrict__ gamma,
                                             const float* __restrict__ beta) {
  const int row = blockIdx.x, tid = threadIdx.x;
  float4v v = ((const float4v*)y)[row * 256 + tid];
  float s = v.x + v.y + v.z + v.w;
  float ss = v.x * v.x + v.y * v.y + v.z * v.z + v.w * v.w;
#pragma unroll
  for (int o = 1; o < 64; o <<= 1) { s += __shfl_xor(s, o); ss += __shfl_xor(ss, o); }
  __shared__ float sb[8];
  const int wv = tid >> 6, lane = tid & 63;
  if (lane == 0) { sb[wv] = s; sb[4 + wv] = ss; }
  __syncthreads();
  s = sb[0] + sb[1] + sb[2] + sb[3];
  ss = sb[4] + sb[5] + sb[6] + sb[7];
  const float mu = s * (1.0f / 1024.0f);
  const float var = ss * (1.0f / 1024.0f) - mu * mu;
  const float rstd = rsqrtf(var + 1e-3f);
  float4v g = ((const float4v*)gamma)[tid];
  float4v bb = ((const float4v*)beta)[tid];
  float4v o;
  o.x = (v.x - mu) * rstd * g.x + bb.x;
  o.y = (v.y - mu) * rstd * g.y + bb.y;
  o.z = (v.z - mu) * rstd * g.z + bb.z;
  o.w = (v.w - mu) * rstd * g.w + bb.w;
  ((float4v*)y)[row * 256 + tid] = o;
}

// ---------------- launch ----------------

extern "C" void kernel_launch(void* const* d_in, const int* in_sizes, int n_in,
                              void* d_out, int out_size, void* d_ws, size_t ws_size,
                              hipStream_t stream) {
  const float* x     = (const float*)d_in[0];
  const float* Wq    = (const float*)d_in[1];
  const float* Wk    = (const float*)d_in[2];
  const float* Wv    = (const float*)d_in[3];
  const float* Wo    = (const float*)d_in[4];
  const float* gamma = (const float*)d_in[5];
  const float* beta  = (const float*)d_in[6];
  float* out = (float*)d_out;

  char* ws = (char*)d_ws;
  bf16* xb    = (bf16*)(ws);                    // 16 MiB  (reused as heads)
  bf16* wqkvt = (bf16*)(ws + 16777216);         // 6 MiB
  bf16* wot   = (bf16*)(ws + 23068672);         // 2 MiB
  bf16* Qb    = (bf16*)(ws + 25165824);         // 16 MiB
  bf16* Kb    = (bf16*)(ws + 41943040);         // 16 MiB
  bf16* Vtb   = (bf16*)(ws + 58720256);         // 16 MiB
  bf16* heads = xb;                             // alias: xb dead after gemm_qkv

  packs<<<9216, 256, 0, stream>>>(x, Wq, Wk, Wv, Wo, xb, wqkvt, wot);
  gemm128<0><<<dim3(24, 64), 256, 0, stream>>>(xb, wqkvt, D_, Qb, Kb, Vtb, nullptr, nullptr);
  attn<<<64 * 8, 512, 0, stream>>>(Qb, Kb, Vtb, heads);
  gemm128<1><<<dim3(8, 64), 256, 0, stream>>>(heads, wot, D_, nullptr, nullptr, nullptr, x, out);
  lnorm<<<M_, 256, 0, stream>>>(out, gamma, beta);
}

// Round 7
// 249.621 us; speedup vs baseline: 1.0333x; 1.0333x over previous
//
#include <hip/hip_runtime.h>
#include <stdint.h>

typedef __bf16 bf16;
typedef float  f32x4  __attribute__((ext_vector_type(4)));
typedef float  float4v __attribute__((ext_vector_type(4)));
typedef bf16   bf16x8 __attribute__((ext_vector_type(8)));
typedef bf16   bf16x4 __attribute__((ext_vector_type(4)));

#define B_ 4
#define S_ 2048
#define D_ 1024
#define H_ 16
#define E_ 64
#define M_ 8192   // B_*S_
// Q prescale: 1/sqrt(E) * log2(e)  -> scores come out in log2 domain
#define QSCALE 0.18033688f

// NOTE (session journal): inline `s_waitcnt` asm and prefetch-after-barrier
// staging each killed the MI355X container twice in the prior session.
// Stage -> __syncthreads -> compute is proven. Do not reintroduce either.
// R1: attn 512-thr / 8-wave blocks, 128-row q-tile pair {A,15-A}: 61.5->~58us.
// R3 FAILED: KVBLK=128 + V-direct-from-global -> 160us. V MUST stay LDS-staged
//   (PV re-reads the V tile 16x). wall - sum(dispatch) ~ 75us is FIXED harness
//   overhead -> kernel fusion not a lever.
// R4: attn v5 + T5 setprio -> 253.6us; gemm_qkv top at 60us = 858 TF.
// R5: __launch_bounds__(256,4) NEUTRAL -> gemm at the 2-barrier structural
//   ceiling (~880 TF); counted-vmcnt / dbuf-prefetch paths are banned.
// R6 FAILED: 32x32x16 MFMA -> 80us, BANK_CONFLICT 0 -> 6.29M. With 32-row
//   fragments the bank group depends only on the 16B chunk (row stride 128B
//   = 0 mod 32 banks) -> 8 lanes/chunk = 8-way conflict. The XOR swizzle is
//   conflict-free ONLY with 16-row quad-group reads. 16x16 is load-bearing.
// R7 (this round): revert gemm to R5-exact; attn: hoist K fragments out of
//   the t-loop (k0/k1 are t-invariant; 16->8 ds_read_b128 per wave per iter,
//   +32 VGPR ~ 96 < 128 cap).

// async global->LDS, 16B per lane. LDS dest must be wave-uniform base + lane*16.
__device__ __forceinline__ void async_ld16(const bf16* g, bf16* l) {
  __builtin_amdgcn_global_load_lds(
      (const __attribute__((address_space(1))) void*)g,
      (__attribute__((address_space(3))) void*)l, 16, 0, 0);
}

// ---------------- fused pack kernel ----------------
// blocks [0,8192): x f32 -> bf16 cast (no LDS, no sync)
// blocks [8192,8960): Wq/Wk/Wv [H][D][E] -> Bt[n][d], n = qkv*1024+h*64+e
// blocks [8960,9216): Wo [K][N] -> Wot[n][k]

__global__ __launch_bounds__(256) void packs(
    const float* __restrict__ x, const float* __restrict__ Wq,
    const float* __restrict__ Wk, const float* __restrict__ Wv,
    const float* __restrict__ Wo, bf16* __restrict__ xb,
    bf16* __restrict__ Bt, bf16* __restrict__ Wot) {
  __shared__ float t[64][65];
  const int bid = blockIdx.x;
  if (bid < 8192) {                       // ---- pack_x: 8192*256 float4 ----
    int i = bid * 256 + threadIdx.x;      // n4 = 2097152 exactly = 8192*256
    float4v v = ((const float4v*)x)[i];
    bf16x4 o = { (bf16)v.x, (bf16)v.y, (bf16)v.z, (bf16)v.w };
    ((bf16x4*)xb)[i] = o;
    return;
  }
  const int tr = threadIdx.x >> 2;        // 0..63
  const int tc = (threadIdx.x & 3) * 16;  // 0,16,32,48
  if (bid < 8960) {                       // ---- pack_wqkv: 768 blocks ----
    const int fb = bid - 8192;
    const int mat = fb % 48;              // qkv*16 + h
    const int d0 = (fb / 48) * 64;
    const int qkv = mat >> 4, h = mat & 15;
    const float* W = (qkv == 0) ? Wq : ((qkv == 1) ? Wk : Wv);
    const float* src = W + h * (D_ * E_);           // [d][e]
    for (int i = 0; i < 16; ++i) t[tr][tc + i] = src[(d0 + tr) * E_ + tc + i];
    __syncthreads();
    const int n = qkv * 1024 + h * 64 + tr;         // output row (e dim)
    bf16* dst = Bt + n * D_ + d0 + tc;
    for (int i = 0; i < 16; ++i) dst[i] = (bf16)t[tc + i][tr];
  } else {                                // ---- pack_wo: 256 blocks ----
    const int fb = bid - 8960;
    const int k0 = (fb & 15) * 64, n0 = (fb >> 4) * 64;
    for (int i = 0; i < 16; ++i) t[tr][tc + i] = Wo[(k0 + tr) * D_ + n0 + tc + i];
    __syncthreads();
    bf16* dst = Wot + (n0 + tr) * D_ + k0 + tc;
    for (int i = 0; i < 16; ++i) dst[i] = (bf16)t[tc + i][tr];
  }
}

// ---------------- 128x128 MFMA GEMM (m97 structure, XOR-swizzled LDS) ----------

template <int EPI>
__global__ __launch_bounds__(256, 4) void gemm128(
    const bf16* __restrict__ A, const bf16* __restrict__ Bt, int K,
    bf16* __restrict__ qo, bf16* __restrict__ ko, bf16* __restrict__ vt,
    const float* __restrict__ xres, float* __restrict__ outp) {
  __shared__ bf16 As[128 * 64];
  __shared__ bf16 Bs[128 * 64];
  const int tid = threadIdx.x;
  const int wave = tid >> 6, lane = tid & 63;
  const int lm = lane & 15, quad = lane >> 4;
  const int wr = wave >> 1, wc = wave & 1;
  const int m0 = blockIdx.y * 128, n0 = blockIdx.x * 128;
  f32x4 acc[4][4] = {};

  for (int kt = 0; kt < K; kt += 64) {
    for (int it = 0; it < 4; ++it) {
      int cl = it * 256 + tid;       // chunk id 0..1023 (16B chunks)
      int r = cl >> 3, pc = cl & 7;
      int cc = pc ^ (r & 7);         // source column-chunk (XOR swizzle, self-inverse)
      async_ld16(A + (m0 + r) * K + kt + cc * 8, As + cl * 8);
      async_ld16(Bt + (n0 + r) * K + kt + cc * 8, Bs + cl * 8);
    }
    __syncthreads();
    for (int kk = 0; kk < 64; kk += 32) {
      bf16x8 af[4], bfr[4];
      const int ccb = (kk >> 3) + quad;
      for (int i = 0; i < 4; ++i) {
        int row = wr * 64 + i * 16 + lm;
        af[i] = *(const bf16x8*)(As + row * 64 + (ccb ^ (row & 7)) * 8);
      }
      for (int j = 0; j < 4; ++j) {
        int row = wc * 64 + j * 16 + lm;
        bfr[j] = *(const bf16x8*)(Bs + row * 64 + (ccb ^ (row & 7)) * 8);
      }
      for (int i = 0; i < 4; ++i)
        for (int j = 0; j < 4; ++j)
          acc[i][j] = __builtin_amdgcn_mfma_f32_16x16x32_bf16(af[i], bfr[j], acc[i][j], 0, 0, 0);
    }
    __syncthreads();
  }

  if (EPI == 0) {
    const int qkv = n0 >> 10;                    // uniform per block (1024%128==0)
    const int hh = ((n0 + wc * 64) >> 6) & 15;   // uniform per wave
    for (int i = 0; i < 4; ++i) {
      const int gm0 = m0 + wr * 64 + i * 16 + quad * 4;
      const int b = gm0 >> 11, s0 = gm0 & 2047;  // 4 rows share b (gm0 % 4 == 0)
      for (int j = 0; j < 4; ++j) {
        const int e = j * 16 + lm;
        if (qkv == 2) {
          bf16x4 pv = { (bf16)acc[i][j][0], (bf16)acc[i][j][1],
                        (bf16)acc[i][j][2], (bf16)acc[i][j][3] };
          *(bf16x4*)(vt + (((b << 4) + hh) * 64 + e) * (size_t)S_ + s0) = pv;
        } else if (qkv == 0) {
          for (int r = 0; r < 4; ++r)
            qo[(((b << 4) + hh) * S_ + (s0 + r)) * (size_t)E_ + e] =
                (bf16)(acc[i][j][r] * QSCALE);   // fold 1/sqrt(E)*log2e here
        } else {
          for (int r = 0; r < 4; ++r)
            ko[(((b << 4) + hh) * S_ + (s0 + r)) * (size_t)E_ + e] = (bf16)acc[i][j][r];
        }
      }
    }
  } else {
    for (int i = 0; i < 4; ++i)
      for (int r = 0; r < 4; ++r) {
        const int gm = m0 + wr * 64 + i * 16 + quad * 4 + r;
        for (int j = 0; j < 4; ++j) {
          const int gn = n0 + wc * 64 + j * 16 + lm;
          outp[gm * (size_t)D_ + gn] = acc[i][j][r] + xres[gm * (size_t)D_ + gn];
        }
      }
  }
}

// -------- flash attention v5.1: v5 + T5 setprio + K-frag hoist --------------
// Q,K: [B,H,S,E] bf16 (Q pre-scaled by log2e/8 -> scores in log2 domain).
// Vt: [B,H,E,S] bf16. Block = (b,h, q-128-tile pair {At, 15-At}); 8 waves,
// wave w owns rows w*16 of BOTH tiles -> per-iteration work balanced.
// K and V both LDS-staged (R3 lesson). Stage -> sync -> compute, dbuf, proven.
// K fragments are t-invariant -> read once per staged tile into kf0/kf1
// (8 ds_read_b128 instead of 16 per wave per iter).

__global__ __launch_bounds__(512, 4) void attn(
    const bf16* __restrict__ Q, const bf16* __restrict__ Kb,
    const bf16* __restrict__ Vt, bf16* __restrict__ Hd) {
  __shared__ __align__(16) bf16 Ks[2][64 * 64];
  __shared__ __align__(16) bf16 Vs[2][64 * 64];
  __shared__ __align__(16) bf16 Pb[8][16 * 64];   // per-wave P (t-shared)
  const int tid = threadIdx.x;
  const int w = tid >> 6, lane = tid & 63;
  const int lm = lane & 15, quad = lane >> 4;
  const int l7 = lm & 7;
  const int bi = blockIdx.x;
  const int bh = bi & 63;             // b*16+h
  const int At = bi >> 6;             // 0..7 : q-128-tile pair {At, 15-At}
  const bf16* Qp = Q + (size_t)bh * S_ * E_;
  const bf16* Kp = Kb + (size_t)bh * S_ * E_;
  const bf16* Vp = Vt + (size_t)bh * E_ * S_;

  int qb[2], sq[2];
  bf16x8 qf[2][2];
  qb[0] = At * 128 + w * 16;
  qb[1] = (15 - At) * 128 + w * 16;
#pragma unroll
  for (int t = 0; t < 2; ++t) {
    sq[t] = qb[t] + lm;
    qf[t][0] = *(const bf16x8*)(Qp + sq[t] * E_ + quad * 8);
    qf[t][1] = *(const bf16x8*)(Qp + sq[t] * E_ + 32 + quad * 8);
  }
  float ls[2] = { 0.0f, 0.0f };       // per-lane partial row sums
  f32x4 oacc[2][4] = {};

  const int jmax = 31 - 2 * At;       // diag 64-tile of the larger q-tile
  for (int j = 0; j <= jmax; ++j) {
    const int p = j & 1;
    const int sk0 = j * 64;
    // stage K tile [sk0..sk0+63][0..63] and V^T tile [0..63][sk0..sk0+63]
    {
      int cl = tid;                   // 0..511 16B chunks (one K + one V each)
      int r = cl >> 3, pc = cl & 7;
      int cc = pc ^ (r & 7);
      async_ld16(Kp + (sk0 + r) * E_ + cc * 8, &Ks[p][cl * 8]);
      async_ld16(Vp + (size_t)r * S_ + sk0 + cc * 8, &Vs[p][cl * 8]);
    }
    __syncthreads();                  // stage -> barrier (proven structure)

    // ---- K fragments: t-invariant, read once per staged tile ----
    bf16x8 kf0[4], kf1[4];
#pragma unroll
    for (int i = 0; i < 4; ++i) {
      const int row = i * 16 + lm;
      kf0[i] = *(const bf16x8*)(&Ks[p][row * 64 + (quad ^ l7) * 8]);
      kf1[i] = *(const bf16x8*)(&Ks[p][row * 64 + ((4 + quad) ^ l7) * 8]);
    }

#pragma unroll
    for (int t = 0; t < 2; ++t) {
      const int d = (qb[t] - sk0) >> 4;   // diagonal subtile index (wave-uniform)
      if (d < 0) continue;                // whole tile above diagonal
      // ---- QK: always all 4 sk-subtiles (compile-time unroll) ----
      f32x4 st[4] = {};
      __builtin_amdgcn_s_setprio(1);
#pragma unroll
      for (int i = 0; i < 4; ++i) {
        st[i] = __builtin_amdgcn_mfma_f32_16x16x32_bf16(kf0[i], qf[t][0], st[i], 0, 0, 0);
        st[i] = __builtin_amdgcn_mfma_f32_16x16x32_bf16(kf1[i], qf[t][1], st[i], 0, 0, 0);
      }
      __builtin_amdgcn_s_setprio(0);
      if (d < 4) {                        // diagonal tile: mask sk>sq
#pragma unroll
        for (int i = 0; i < 4; ++i) {
          const int base = (i - d) * 16 + quad * 4;   // <=-1 below diag
#pragma unroll
          for (int r = 0; r < 4; ++r)
            st[i][r] = (base + r > lm) ? -30000.0f : st[i][r];
        }
      }
      // ---- softmax (max-free): p = exp2(s); per-lane row-sum ----
      char* pbase = (char*)&Pb[w][0];
#pragma unroll
      for (int i = 0; i < 4; ++i) {
        const float p0 = __builtin_amdgcn_exp2f(st[i][0]);
        const float p1 = __builtin_amdgcn_exp2f(st[i][1]);
        const float p2 = __builtin_amdgcn_exp2f(st[i][2]);
        const float p3 = __builtin_amdgcn_exp2f(st[i][3]);
        ls[t] += (p0 + p1) + (p2 + p3);
        bf16x4 pv = { (bf16)p0, (bf16)p1, (bf16)p2, (bf16)p3 };
        const int c = (i * 2 + (quad >> 1)) ^ l7;
        *(bf16x4*)(pbase + lm * 128 + c * 16 + (quad & 1) * 8) = pv;
      }
      // ---- PV: O^T += V^T · P^T, 2 k-steps (compile-time) ----
      __builtin_amdgcn_s_setprio(1);
#pragma unroll
      for (int ks = 0; ks < 2; ++ks) {
        bf16x8 pf = *(const bf16x8*)(pbase + lm * 128 + ((ks * 4 + quad) ^ l7) * 16);
#pragma unroll
        for (int te = 0; te < 4; ++te) {
          const int vrow = te * 16 + lm;
          bf16x8 vf = *(const bf16x8*)(&Vs[p][vrow * 64 + ((ks * 4 + quad) ^ l7) * 8]);
          oacc[t][te] = __builtin_amdgcn_mfma_f32_16x16x32_bf16(vf, pf, oacc[t][te], 0, 0, 0);
        }
      }
      __builtin_amdgcn_s_setprio(0);
    }
  }
  const int b = bh >> 4, h = bh & 15;
#pragma unroll
  for (int t = 0; t < 2; ++t) {
    float rs = ls[t];
    rs += __shfl_xor(rs, 16);
    rs += __shfl_xor(rs, 32);
    const float inv = 1.0f / rs;
#pragma unroll
    for (int te = 0; te < 4; ++te) {
      bf16x4 ov = { (bf16)(oacc[t][te][0] * inv), (bf16)(oacc[t][te][1] * inv),
                    (bf16)(oacc[t][te][2] * inv), (bf16)(oacc[t][te][3] * inv) };
      *(bf16x4*)(&Hd[((size_t)b * S_ + sq[t]) * D_ + h * 64 + te * 16 + quad * 4]) = ov;
    }
  }
}

// ---------------- rowwise LayerNorm, in-place on f32 ----------------

__global__ __launch_bounds__(256) void lnorm(float* __restrict__ y,
                                             const float* __restrict__ gamma,
                                             const float* __restrict__ beta) {
  const int row = blockIdx.x, tid = threadIdx.x;
  float4v v = ((const float4v*)y)[row * 256 + tid];
  float s = v.x + v.y + v.z + v.w;
  float ss = v.x * v.x + v.y * v.y + v.z * v.z + v.w * v.w;
#pragma unroll
  for (int o = 1; o < 64; o <<= 1) { s += __shfl_xor(s, o); ss += __shfl_xor(ss, o); }
  __shared__ float sb[8];
  const int wv = tid >> 6, lane = tid & 63;
  if (lane == 0) { sb[wv] = s; sb[4 + wv] = ss; }
  __syncthreads();
  s = sb[0] + sb[1] + sb[2] + sb[3];
  ss = sb[4] + sb[5] + sb[6] + sb[7];
  const float mu = s * (1.0f / 1024.0f);
  const float var = ss * (1.0f / 1024.0f) - mu * mu;
  const float rstd = rsqrtf(var + 1e-3f);
  float4v g = ((const float4v*)gamma)[tid];
  float4v bb = ((const float4v*)beta)[tid];
  float4v o;
  o.x = (v.x - mu) * rstd * g.x + bb.x;
  o.y = (v.y - mu) * rstd * g.y + bb.y;
  o.z = (v.z - mu) * rstd * g.z + bb.z;
  o.w = (v.w - mu) * rstd * g.w + bb.w;
  ((float4v*)y)[row * 256 + tid] = o;
}

// ---------------- launch ----------------

extern "C" void kernel_launch(void* const* d_in, const int* in_sizes, int n_in,
                              void* d_out, int out_size, void* d_ws, size_t ws_size,
                              hipStream_t stream) {
  const float* x     = (const float*)d_in[0];
  const float* Wq    = (const float*)d_in[1];
  const float* Wk    = (const float*)d_in[2];
  const float* Wv    = (const float*)d_in[3];
  const float* Wo    = (const float*)d_in[4];
  const float* gamma = (const float*)d_in[5];
  const float* beta  = (const float*)d_in[6];
  float* out = (float*)d_out;

  char* ws = (char*)d_ws;
  bf16* xb    = (bf16*)(ws);                    // 16 MiB  (reused as heads)
  bf16* wqkvt = (bf16*)(ws + 16777216);         // 6 MiB
  bf16* wot   = (bf16*)(ws + 23068672);         // 2 MiB
  bf16* Qb    = (bf16*)(ws + 25165824);         // 16 MiB
  bf16* Kb    = (bf16*)(ws + 41943040);         // 16 MiB
  bf16* Vtb   = (bf16*)(ws + 58720256);         // 16 MiB
  bf16* heads = xb;                             // alias: xb dead after gemm_qkv

  packs<<<9216, 256, 0, stream>>>(x, Wq, Wk, Wv, Wo, xb, wqkvt, wot);
  gemm128<0><<<dim3(24, 64), 256, 0, stream>>>(xb, wqkvt, D_, Qb, Kb, Vtb, nullptr, nullptr);
  attn<<<64 * 8, 512, 0, stream>>>(Qb, Kb, Vtb, heads);
  gemm128<1><<<dim3(8, 64), 256, 0, stream>>>(heads, wot, D_, nullptr, nullptr, nullptr, x, out);
  lnorm<<<M_, 256, 0, stream>>>(out, gamma, beta);
}

// Round 9
// 245.559 us; speedup vs baseline: 1.0504x; 1.0165x over previous
//
#include <hip/hip_runtime.h>
#include <stdint.h>

typedef __bf16 bf16;
typedef float  f32x4  __attribute__((ext_vector_type(4)));
typedef float  float4v __attribute__((ext_vector_type(4)));
typedef bf16   bf16x8 __attribute__((ext_vector_type(8)));
typedef bf16   bf16x4 __attribute__((ext_vector_type(4)));

#define B_ 4
#define S_ 2048
#define D_ 1024
#define H_ 16
#define E_ 64
#define M_ 8192   // B_*S_
// Q prescale: 1/sqrt(E) * log2(e)  -> scores come out in log2 domain
#define QSCALE 0.18033688f

// NOTE (session journal): inline `s_waitcnt` asm and prefetch-after-barrier
// staging each killed the MI355X container twice in the prior session.
// Stage -> __syncthreads -> compute is proven. Do not reintroduce either.
// R1: attn 512-thr / 8-wave blocks, q-128-tile pair {At,15-At}.
// R3 FAILED: V-direct-from-global -> 160us (PV re-reads V 16x; V stays in LDS).
//   wall - sum(dispatch) ~75us is FIXED harness overhead; fusion not a lever.
// R4: + T5 setprio on attn MFMA clusters -> 253.6us.
// R5: launch_bounds(256,4) NEUTRAL -> gemm at the 2-barrier structural
//   ceiling (~880 TF); counted-vmcnt / dbuf-prefetch paths banned.
// R6 FAILED: 32x32x16 MFMA -> 8-way LDS conflicts (row stride 128B = 0 mod
//   32 banks; 16-row quad-group reads are what make the XOR swizzle free).
// R7: K-frag hoist (t-invariant) -> 249.6us best.
// R8: combined PV (Pb[w][t], V fragment read once). Container failed twice
//   WITHOUT counters -- same signature as R0, where the proven kernel also
//   "failed twice" then passed unchanged. Audit found no banned construct,
//   no barrier divergence, LDS 64KB OK, addresses in bounds.
// R9 (this round): resubmit R8 byte-identical (infra-flake test, R0
//   precedent). If it fails again -> code implicated -> revert to R7.

// async global->LDS, 16B per lane. LDS dest must be wave-uniform base + lane*16.
__device__ __forceinline__ void async_ld16(const bf16* g, bf16* l) {
  __builtin_amdgcn_global_load_lds(
      (const __attribute__((address_space(1))) void*)g,
      (__attribute__((address_space(3))) void*)l, 16, 0, 0);
}

// ---------------- fused pack kernel ----------------
// blocks [0,8192): x f32 -> bf16 cast (no LDS, no sync)
// blocks [8192,8960): Wq/Wk/Wv [H][D][E] -> Bt[n][d], n = qkv*1024+h*64+e
// blocks [8960,9216): Wo [K][N] -> Wot[n][k]

__global__ __launch_bounds__(256) void packs(
    const float* __restrict__ x, const float* __restrict__ Wq,
    const float* __restrict__ Wk, const float* __restrict__ Wv,
    const float* __restrict__ Wo, bf16* __restrict__ xb,
    bf16* __restrict__ Bt, bf16* __restrict__ Wot) {
  __shared__ float t[64][65];
  const int bid = blockIdx.x;
  if (bid < 8192) {                       // ---- pack_x: 8192*256 float4 ----
    int i = bid * 256 + threadIdx.x;      // n4 = 2097152 exactly = 8192*256
    float4v v = ((const float4v*)x)[i];
    bf16x4 o = { (bf16)v.x, (bf16)v.y, (bf16)v.z, (bf16)v.w };
    ((bf16x4*)xb)[i] = o;
    return;
  }
  const int tr = threadIdx.x >> 2;        // 0..63
  const int tc = (threadIdx.x & 3) * 16;  // 0,16,32,48
  if (bid < 8960) {                       // ---- pack_wqkv: 768 blocks ----
    const int fb = bid - 8192;
    const int mat = fb % 48;              // qkv*16 + h
    const int d0 = (fb / 48) * 64;
    const int qkv = mat >> 4, h = mat & 15;
    const float* W = (qkv == 0) ? Wq : ((qkv == 1) ? Wk : Wv);
    const float* src = W + h * (D_ * E_);           // [d][e]
    for (int i = 0; i < 16; ++i) t[tr][tc + i] = src[(d0 + tr) * E_ + tc + i];
    __syncthreads();
    const int n = qkv * 1024 + h * 64 + tr;         // output row (e dim)
    bf16* dst = Bt + n * D_ + d0 + tc;
    for (int i = 0; i < 16; ++i) dst[i] = (bf16)t[tc + i][tr];
  } else {                                // ---- pack_wo: 256 blocks ----
    const int fb = bid - 8960;
    const int k0 = (fb & 15) * 64, n0 = (fb >> 4) * 64;
    for (int i = 0; i < 16; ++i) t[tr][tc + i] = Wo[(k0 + tr) * D_ + n0 + tc + i];
    __syncthreads();
    bf16* dst = Wot + (n0 + tr) * D_ + k0 + tc;
    for (int i = 0; i < 16; ++i) dst[i] = (bf16)t[tc + i][tr];
  }
}

// ---------------- 128x128 MFMA GEMM (m97 structure, XOR-swizzled LDS) ----------

template <int EPI>
__global__ __launch_bounds__(256, 4) void gemm128(
    const bf16* __restrict__ A, const bf16* __restrict__ Bt, int K,
    bf16* __restrict__ qo, bf16* __restrict__ ko, bf16* __restrict__ vt,
    const float* __restrict__ xres, float* __restrict__ outp) {
  __shared__ bf16 As[128 * 64];
  __shared__ bf16 Bs[128 * 64];
  const int tid = threadIdx.x;
  const int wave = tid >> 6, lane = tid & 63;
  const int lm = lane & 15, quad = lane >> 4;
  const int wr = wave >> 1, wc = wave & 1;
  const int m0 = blockIdx.y * 128, n0 = blockIdx.x * 128;
  f32x4 acc[4][4] = {};

  for (int kt = 0; kt < K; kt += 64) {
    for (int it = 0; it < 4; ++it) {
      int cl = it * 256 + tid;       // chunk id 0..1023 (16B chunks)
      int r = cl >> 3, pc = cl & 7;
      int cc = pc ^ (r & 7);         // source column-chunk (XOR swizzle, self-inverse)
      async_ld16(A + (m0 + r) * K + kt + cc * 8, As + cl * 8);
      async_ld16(Bt + (n0 + r) * K + kt + cc * 8, Bs + cl * 8);
    }
    __syncthreads();
    for (int kk = 0; kk < 64; kk += 32) {
      bf16x8 af[4], bfr[4];
      const int ccb = (kk >> 3) + quad;
      for (int i = 0; i < 4; ++i) {
        int row = wr * 64 + i * 16 + lm;
        af[i] = *(const bf16x8*)(As + row * 64 + (ccb ^ (row & 7)) * 8);
      }
      for (int j = 0; j < 4; ++j) {
        int row = wc * 64 + j * 16 + lm;
        bfr[j] = *(const bf16x8*)(Bs + row * 64 + (ccb ^ (row & 7)) * 8);
      }
      for (int i = 0; i < 4; ++i)
        for (int j = 0; j < 4; ++j)
          acc[i][j] = __builtin_amdgcn_mfma_f32_16x16x32_bf16(af[i], bfr[j], acc[i][j], 0, 0, 0);
    }
    __syncthreads();
  }

  if (EPI == 0) {
    const int qkv = n0 >> 10;                    // uniform per block (1024%128==0)
    const int hh = ((n0 + wc * 64) >> 6) & 15;   // uniform per wave
    for (int i = 0; i < 4; ++i) {
      const int gm0 = m0 + wr * 64 + i * 16 + quad * 4;
      const int b = gm0 >> 11, s0 = gm0 & 2047;  // 4 rows share b (gm0 % 4 == 0)
      for (int j = 0; j < 4; ++j) {
        const int e = j * 16 + lm;
        if (qkv == 2) {
          bf16x4 pv = { (bf16)acc[i][j][0], (bf16)acc[i][j][1],
                        (bf16)acc[i][j][2], (bf16)acc[i][j][3] };
          *(bf16x4*)(vt + (((b << 4) + hh) * 64 + e) * (size_t)S_ + s0) = pv;
        } else if (qkv == 0) {
          for (int r = 0; r < 4; ++r)
            qo[(((b << 4) + hh) * S_ + (s0 + r)) * (size_t)E_ + e] =
                (bf16)(acc[i][j][r] * QSCALE);   // fold 1/sqrt(E)*log2e here
        } else {
          for (int r = 0; r < 4; ++r)
            ko[(((b << 4) + hh) * S_ + (s0 + r)) * (size_t)E_ + e] = (bf16)acc[i][j][r];
        }
      }
    }
  } else {
    for (int i = 0; i < 4; ++i)
      for (int r = 0; r < 4; ++r) {
        const int gm = m0 + wr * 64 + i * 16 + quad * 4 + r;
        for (int j = 0; j < 4; ++j) {
          const int gn = n0 + wc * 64 + j * 16 + lm;
          outp[gm * (size_t)D_ + gn] = acc[i][j][r] + xres[gm * (size_t)D_ + gn];
        }
      }
  }
}

// -------- flash attention v5.2: K-frag hoist + combined PV ------------------
// Q,K: [B,H,S,E] bf16 (Q pre-scaled by log2e/8 -> scores in log2 domain).
// Vt: [B,H,E,S] bf16. Block = (b,h, q-128-tile pair {At, 15-At}); 8 waves,
// wave w owns rows w*16 of BOTH tiles. K and V LDS-staged (R3 lesson).
// Both P tiles kept in Pb[w][t]; single PV pass reads each V fragment once
// and feeds both tiles' MFMAs when both are active (wave-uniform guards).

__global__ __launch_bounds__(512, 4) void attn(
    const bf16* __restrict__ Q, const bf16* __restrict__ Kb,
    const bf16* __restrict__ Vt, bf16* __restrict__ Hd) {
  __shared__ __align__(16) bf16 Ks[2][64 * 64];
  __shared__ __align__(16) bf16 Vs[2][64 * 64];
  __shared__ __align__(16) bf16 Pb[8][2][16 * 64];  // per-wave, per-tile P
  const int tid = threadIdx.x;
  const int w = tid >> 6, lane = tid & 63;
  const int lm = lane & 15, quad = lane >> 4;
  const int l7 = lm & 7;
  const int bi = blockIdx.x;
  const int bh = bi & 63;             // b*16+h
  const int At = bi >> 6;             // 0..7 : q-128-tile pair {At, 15-At}
  const bf16* Qp = Q + (size_t)bh * S_ * E_;
  const bf16* Kp = Kb + (size_t)bh * S_ * E_;
  const bf16* Vp = Vt + (size_t)bh * E_ * S_;

  int qb[2], sq[2];
  bf16x8 qf[2][2];
  qb[0] = At * 128 + w * 16;
  qb[1] = (15 - At) * 128 + w * 16;
#pragma unroll
  for (int t = 0; t < 2; ++t) {
    sq[t] = qb[t] + lm;
    qf[t][0] = *(const bf16x8*)(Qp + sq[t] * E_ + quad * 8);
    qf[t][1] = *(const bf16x8*)(Qp + sq[t] * E_ + 32 + quad * 8);
  }
  float ls[2] = { 0.0f, 0.0f };       // per-lane partial row sums
  f32x4 oacc[2][4] = {};

  const int jmax = 31 - 2 * At;       // diag 64-tile of the larger q-tile
  for (int j = 0; j <= jmax; ++j) {
    const int p = j & 1;
    const int sk0 = j * 64;
    // stage K tile [sk0..sk0+63][0..63] and V^T tile [0..63][sk0..sk0+63]
    {
      int cl = tid;                   // 0..511 16B chunks (one K + one V each)
      int r = cl >> 3, pc = cl & 7;
      int cc = pc ^ (r & 7);
      async_ld16(Kp + (sk0 + r) * E_ + cc * 8, &Ks[p][cl * 8]);
      async_ld16(Vp + (size_t)r * S_ + sk0 + cc * 8, &Vs[p][cl * 8]);
    }
    __syncthreads();                  // stage -> barrier (proven structure)

    // ---- K fragments: t-invariant, read once per staged tile ----
    bf16x8 kf0[4], kf1[4];
#pragma unroll
    for (int i = 0; i < 4; ++i) {
      const int row = i * 16 + lm;
      kf0[i] = *(const bf16x8*)(&Ks[p][row * 64 + (quad ^ l7) * 8]);
      kf1[i] = *(const bf16x8*)(&Ks[p][row * 64 + ((4 + quad) ^ l7) * 8]);
    }

    // ---- QK + softmax per tile, P -> Pb[w][t] ----
#pragma unroll
    for (int t = 0; t < 2; ++t) {
      const int d = (qb[t] - sk0) >> 4;   // diagonal subtile index (wave-uniform)
      if (d < 0) continue;                // whole tile above diagonal
      f32x4 st[4] = {};
      __builtin_amdgcn_s_setprio(1);
#pragma unroll
      for (int i = 0; i < 4; ++i) {
        st[i] = __builtin_amdgcn_mfma_f32_16x16x32_bf16(kf0[i], qf[t][0], st[i], 0, 0, 0);
        st[i] = __builtin_amdgcn_mfma_f32_16x16x32_bf16(kf1[i], qf[t][1], st[i], 0, 0, 0);
      }
      __builtin_amdgcn_s_setprio(0);
      if (d < 4) {                        // diagonal tile: mask sk>sq
#pragma unroll
        for (int i = 0; i < 4; ++i) {
          const int base = (i - d) * 16 + quad * 4;   // <=-1 below diag
#pragma unroll
          for (int r = 0; r < 4; ++r)
            st[i][r] = (base + r > lm) ? -30000.0f : st[i][r];
        }
      }
      char* pbase = (char*)&Pb[w][t][0];
#pragma unroll
      for (int i = 0; i < 4; ++i) {
        const float p0 = __builtin_amdgcn_exp2f(st[i][0]);
        const float p1 = __builtin_amdgcn_exp2f(st[i][1]);
        const float p2 = __builtin_amdgcn_exp2f(st[i][2]);
        const float p3 = __builtin_amdgcn_exp2f(st[i][3]);
        ls[t] += (p0 + p1) + (p2 + p3);
        bf16x4 pv = { (bf16)p0, (bf16)p1, (bf16)p2, (bf16)p3 };
        const int c = (i * 2 + (quad >> 1)) ^ l7;
        *(bf16x4*)(pbase + lm * 128 + c * 16 + (quad & 1) * 8) = pv;
      }
    }

    // ---- combined PV: O^T += V^T · P^T, V fragment read once ----
    const bool a0 = (qb[0] >= sk0), a1 = (qb[1] >= sk0);  // wave-uniform
    __builtin_amdgcn_s_setprio(1);
#pragma unroll
    for (int ks = 0; ks < 2; ++ks) {
      const int pc16 = ((ks * 4 + quad) ^ l7) * 16;
      bf16x8 pf0 = {}, pf1 = {};
      if (a0) pf0 = *(const bf16x8*)((char*)&Pb[w][0][0] + lm * 128 + pc16);
      if (a1) pf1 = *(const bf16x8*)((char*)&Pb[w][1][0] + lm * 128 + pc16);
#pragma unroll
      for (int te = 0; te < 4; ++te) {
        const int vrow = te * 16 + lm;
        bf16x8 vf = *(const bf16x8*)(&Vs[p][vrow * 64 + ((ks * 4 + quad) ^ l7) * 8]);
        if (a0) oacc[0][te] = __builtin_amdgcn_mfma_f32_16x16x32_bf16(vf, pf0, oacc[0][te], 0, 0, 0);
        if (a1) oacc[1][te] = __builtin_amdgcn_mfma_f32_16x16x32_bf16(vf, pf1, oacc[1][te], 0, 0, 0);
      }
    }
    __builtin_amdgcn_s_setprio(0);
  }
  const int b = bh >> 4, h = bh & 15;
#pragma unroll
  for (int t = 0; t < 2; ++t) {
    float rs = ls[t];
    rs += __shfl_xor(rs, 16);
    rs += __shfl_xor(rs, 32);
    const float inv = 1.0f / rs;
#pragma unroll
    for (int te = 0; te < 4; ++te) {
      bf16x4 ov = { (bf16)(oacc[t][te][0] * inv), (bf16)(oacc[t][te][1] * inv),
                    (bf16)(oacc[t][te][2] * inv), (bf16)(oacc[t][te][3] * inv) };
      *(bf16x4*)(&Hd[((size_t)b * S_ + sq[t]) * D_ + h * 64 + te * 16 + quad * 4]) = ov;
    }
  }
}

// ---------------- rowwise LayerNorm, in-place on f32 ----------------

__global__ __launch_bounds__(256) void lnorm(float* __restrict__ y,
                                             const float* __restrict__ gamma,
                                             const float* __restrict__ beta) {
  const int row = blockIdx.x, tid = threadIdx.x;
  float4v v = ((const float4v*)y)[row * 256 + tid];
  float s = v.x + v.y + v.z + v.w;
  float ss = v.x * v.x + v.y * v.y + v.z * v.z + v.w * v.w;
#pragma unroll
  for (int o = 1; o < 64; o <<= 1) { s += __shfl_xor(s, o); ss += __shfl_xor(ss, o); }
  __shared__ float sb[8];
  const int wv = tid >> 6, lane = tid & 63;
  if (lane == 0) { sb[wv] = s; sb[4 + wv] = ss; }
  __syncthreads();
  s = sb[0] + sb[1] + sb[2] + sb[3];
  ss = sb[4] + sb[5] + sb[6] + sb[7];
  const float mu = s * (1.0f / 1024.0f);
  const float var = ss * (1.0f / 1024.0f) - mu * mu;
  const float rstd = rsqrtf(var + 1e-3f);
  float4v g = ((const float4v*)gamma)[tid];
  float4v bb = ((const float4v*)beta)[tid];
  float4v o;
  o.x = (v.x - mu) * rstd * g.x + bb.x;
  o.y = (v.y - mu) * rstd * g.y + bb.y;
  o.z = (v.z - mu) * rstd * g.z + bb.z;
  o.w = (v.w - mu) * rstd * g.w + bb.w;
  ((float4v*)y)[row * 256 + tid] = o;
}

// ---------------- launch ----------------

extern "C" void kernel_launch(void* const* d_in, const int* in_sizes, int n_in,
                              void* d_out, int out_size, void* d_ws, size_t ws_size,
                              hipStream_t stream) {
  const float* x     = (const float*)d_in[0];
  const float* Wq    = (const float*)d_in[1];
  const float* Wk    = (const float*)d_in[2];
  const float* Wv    = (const float*)d_in[3];
  const float* Wo    = (const float*)d_in[4];
  const float* gamma = (const float*)d_in[5];
  const float* beta  = (const float*)d_in[6];
  float* out = (float*)d_out;

  char* ws = (char*)d_ws;
  bf16* xb    = (bf16*)(ws);                    // 16 MiB  (reused as heads)
  bf16* wqkvt = (bf16*)(ws + 16777216);         // 6 MiB
  bf16* wot   = (bf16*)(ws + 23068672);         // 2 MiB
  bf16* Qb    = (bf16*)(ws + 25165824);         // 16 MiB
  bf16* Kb    = (bf16*)(ws + 41943040);         // 16 MiB
  bf16* Vtb   = (bf16*)(ws + 58720256);         // 16 MiB
  bf16* heads = xb;                             // alias: xb dead after gemm_qkv

  packs<<<9216, 256, 0, stream>>>(x, Wq, Wk, Wv, Wo, xb, wqkvt, wot);
  gemm128<0><<<dim3(24, 64), 256, 0, stream>>>(xb, wqkvt, D_, Qb, Kb, Vtb, nullptr, nullptr);
  attn<<<64 * 8, 512, 0, stream>>>(Qb, Kb, Vtb, heads);
  gemm128<1><<<dim3(8, 64), 256, 0, stream>>>(heads, wot, D_, nullptr, nullptr, nullptr, x, out);
  lnorm<<<M_, 256, 0, stream>>>(out, gamma, beta);
}